// Round 2
// baseline (321.143 us; speedup 1.0000x reference)
//
#include <hip/hip_runtime.h>
#include <hip/hip_bf16.h>
#include <cstdint>

constexpr int Bsz = 2, Seq = 2048, Dim = 1024, NH = 16, HDim = 64;
constexpr int Mtok = Bsz * Seq;           // 4096
constexpr int NQKV = 3 * Dim;             // 3072

typedef __attribute__((ext_vector_type(4))) float f32x4;
typedef __attribute__((ext_vector_type(8))) short bf16x8;

__device__ __forceinline__ ushort f2bf(float f) {
    union { float f; uint32_t u; } v; v.f = f;
    uint32_t u = v.u;
    uint32_t r = (u + 0x7fffu + ((u >> 16) & 1u)) >> 16;
    return (ushort)r;
}

// ---------------- X fp32 -> bf16 ----------------
__global__ void convert_x(const float* __restrict__ in, ushort* __restrict__ out, int n8) {
    int i = blockIdx.x * 256 + threadIdx.x;
    if (i >= n8) return;
    const float4* p = (const float4*)in + (size_t)i * 2;
    float4 a = p[0], b = p[1];
    uint4 o;
    o.x = (uint)f2bf(a.x) | ((uint)f2bf(a.y) << 16);
    o.y = (uint)f2bf(a.z) | ((uint)f2bf(a.w) << 16);
    o.z = (uint)f2bf(b.x) | ((uint)f2bf(b.y) << 16);
    o.w = (uint)f2bf(b.z) | ((uint)f2bf(b.w) << 16);
    ((uint4*)out)[i] = o;
}

// ---------------- W [K][N] fp32 -> W^T [N][K] bf16 (with scale) ----------------
__global__ void transpose_w(const float* __restrict__ src, ushort* __restrict__ dst, float scale) {
    __shared__ float tile[32][33];
    int bx = blockIdx.x * 32, by = blockIdx.y * 32;
    int tx = threadIdx.x, ty = threadIdx.y;  // 32 x 8
#pragma unroll
    for (int j = 0; j < 32; j += 8)
        tile[ty + j][tx] = src[(size_t)(by + ty + j) * Dim + bx + tx];
    __syncthreads();
#pragma unroll
    for (int j = 0; j < 32; j += 8)
        dst[(size_t)(bx + ty + j) * Dim + by + tx] = f2bf(tile[tx][ty + j] * scale);
}

// ---------------- bias concat (bq*0.125, bk, bv) ----------------
__global__ void concat_bias(const float* __restrict__ bq, const float* __restrict__ bk,
                            const float* __restrict__ bv, float* __restrict__ dst) {
    int i = blockIdx.x * 256 + threadIdx.x;
    if (i >= NQKV) return;
    float v = (i < 1024) ? bq[i] * 0.125f : (i < 2048 ? bk[i - 1024] : bv[i - 2048]);
    dst[i] = v;
}

// ---------------- GEMM: C[M][N] = A[M][K]bf16 @ Bt[N][K]bf16^T + bias ----------------
// 128x128 tile, BK=32, 256 threads (4 waves, 2x2), each wave 64x64.
template <bool F32OUT>
__global__ __launch_bounds__(256) void gemm_bt(const ushort* __restrict__ A,
                                               const ushort* __restrict__ Bt,
                                               const float* __restrict__ bias,
                                               void* __restrict__ Cout,
                                               int Msz, int Nsz, int Ksz) {
    __shared__ ushort As[128 * 32];
    __shared__ ushort Bs[128 * 32];
    const int tid = threadIdx.x;
    const int lane = tid & 63, wid = tid >> 6;
    const int wm = wid >> 1, wn = wid & 1;
    const int bm = blockIdx.x * 128, bn = blockIdx.y * 128;
    const int g = lane >> 4, r16 = lane & 15;

    f32x4 acc[4][4] = {};

    const int srow = tid >> 1;       // 0..127
    const int c0 = (tid & 1) * 2;    // chunk 0 or 2

    for (int k0 = 0; k0 < Ksz; k0 += 32) {
        __syncthreads();
        {
            const uint4* ga = (const uint4*)(A + (size_t)(bm + srow) * Ksz + k0);
            uint4 v0 = ga[c0], v1 = ga[c0 + 1];
            *(uint4*)(As + srow * 32 + ((c0 ^ (srow & 3)) * 8)) = v0;
            *(uint4*)(As + srow * 32 + (((c0 + 1) ^ (srow & 3)) * 8)) = v1;
            const uint4* gb = (const uint4*)(Bt + (size_t)(bn + srow) * Ksz + k0);
            uint4 w0 = gb[c0], w1 = gb[c0 + 1];
            *(uint4*)(Bs + srow * 32 + ((c0 ^ (srow & 3)) * 8)) = w0;
            *(uint4*)(Bs + srow * 32 + (((c0 + 1) ^ (srow & 3)) * 8)) = w1;
        }
        __syncthreads();
        bf16x8 af[4], bfr[4];
#pragma unroll
        for (int mt = 0; mt < 4; mt++) {
            int row = wm * 64 + mt * 16 + r16;
            af[mt] = *(const bf16x8*)(As + row * 32 + ((g ^ (row & 3)) * 8));
        }
#pragma unroll
        for (int nt = 0; nt < 4; nt++) {
            int row = wn * 64 + nt * 16 + r16;
            bfr[nt] = *(const bf16x8*)(Bs + row * 32 + ((g ^ (row & 3)) * 8));
        }
#pragma unroll
        for (int mt = 0; mt < 4; mt++)
#pragma unroll
            for (int nt = 0; nt < 4; nt++)
                acc[mt][nt] = __builtin_amdgcn_mfma_f32_16x16x32_bf16(af[mt], bfr[nt], acc[mt][nt], 0, 0, 0);
    }

#pragma unroll
    for (int nt = 0; nt < 4; nt++) {
        int col = bn + wn * 64 + nt * 16 + r16;
        float bv = bias[col];
#pragma unroll
        for (int mt = 0; mt < 4; mt++) {
            int row0 = bm + wm * 64 + mt * 16 + g * 4;
            f32x4 c = acc[mt][nt];
#pragma unroll
            for (int i = 0; i < 4; i++) {
                float v = c[i] + bv;
                if (F32OUT)
                    ((float*)Cout)[(size_t)(row0 + i) * Nsz + col] = v;
                else
                    ((ushort*)Cout)[(size_t)(row0 + i) * Nsz + col] = f2bf(v);
            }
        }
    }
}

// ---------------- V slice of QKV -> VT [bh][d][s] ----------------
__global__ __launch_bounds__(256) void transpose_v(const ushort* __restrict__ QKV,
                                                   ushort* __restrict__ VT) {
    __shared__ ushort t[64][72];
    int bh = blockIdx.y, b = bh >> 4, h = bh & 15;
    int s0 = blockIdx.x * 64;
    int tid = threadIdx.x;
    int r = tid >> 2, cq = (tid & 3) * 16;
    const ushort* src = QKV + (size_t)(b * Seq + s0 + r) * NQKV + 2048 + h * 64 + cq;
    *(uint4*)(&t[r][cq]) = *(const uint4*)src;
    *(uint4*)(&t[r][cq + 8]) = *(const uint4*)(src + 8);
    __syncthreads();
    int d = tid >> 2, sq = (tid & 3) * 16;
    uint u[8];
#pragma unroll
    for (int jj = 0; jj < 8; jj++)
        u[jj] = (uint)t[sq + jj * 2][d] | ((uint)t[sq + jj * 2 + 1][d] << 16);
    uint4 o0 = make_uint4(u[0], u[1], u[2], u[3]);
    uint4 o1 = make_uint4(u[4], u[5], u[6], u[7]);
    uint4* dst = (uint4*)(VT + ((size_t)bh * 64 + d) * Seq + s0 + sq);
    dst[0] = o0;
    dst[1] = o1;
}

// ---------------- flash attention ----------------
// grid (Seq/64, B*H), 256 thr = 4 indep waves, each wave 16 q-rows.
__global__ __launch_bounds__(256) void attn(const ushort* __restrict__ QKV,
                                            const ushort* __restrict__ VT,
                                            ushort* __restrict__ Ctx) {
    __shared__ ushort Plds[4][16 * 72];
    const int tid = threadIdx.x, lane = tid & 63, w = tid >> 6;
    const int bh = blockIdx.y, b = bh >> 4, h = bh & 15;
    const int g = lane >> 4, q16 = lane & 15;
    const int qrow = blockIdx.x * 64 + w * 16;

    const ushort* Qr = QKV + (size_t)(b * Seq + qrow + q16) * NQKV + h * 64;
    bf16x8 qf[2];
    qf[0] = *(const bf16x8*)(Qr + g * 8);
    qf[1] = *(const bf16x8*)(Qr + g * 8 + 32);

    const ushort* Kbase = QKV + (size_t)(b * Seq) * NQKV + 1024 + h * 64;
    const ushort* Vbase = VT + (size_t)bh * 64 * Seq;
    ushort* Pl = Plds[w];

    f32x4 ctxa[4] = {};
    float m_run = -3.0e38f, l_run = 0.f;

    for (int kv0 = 0; kv0 < Seq; kv0 += 64) {
        f32x4 st[4] = {};
#pragma unroll
        for (int t = 0; t < 4; t++) {
            const ushort* kr = Kbase + (size_t)(kv0 + t * 16 + q16) * NQKV;
            bf16x8 ka = *(const bf16x8*)(kr + g * 8);
            bf16x8 kb = *(const bf16x8*)(kr + g * 8 + 32);
            st[t] = __builtin_amdgcn_mfma_f32_16x16x32_bf16(ka, qf[0], st[t], 0, 0, 0);
            st[t] = __builtin_amdgcn_mfma_f32_16x16x32_bf16(kb, qf[1], st[t], 0, 0, 0);
        }
        float mloc = -3.0e38f;
#pragma unroll
        for (int t = 0; t < 4; t++)
#pragma unroll
            for (int i = 0; i < 4; i++) mloc = fmaxf(mloc, st[t][i]);
        mloc = fmaxf(mloc, __shfl_xor(mloc, 16));
        mloc = fmaxf(mloc, __shfl_xor(mloc, 32));
        float m_new = fmaxf(m_run, mloc);
        float alpha = __expf(m_run - m_new);

        float lsum = 0.f;
        ushort pu[4][4];
#pragma unroll
        for (int t = 0; t < 4; t++)
#pragma unroll
            for (int i = 0; i < 4; i++) {
                float p = __expf(st[t][i] - m_new);
                lsum += p;
                pu[t][i] = f2bf(p);
            }
        lsum += __shfl_xor(lsum, 16);
        lsum += __shfl_xor(lsum, 32);
        l_run = l_run * alpha + lsum;
        m_run = m_new;

#pragma unroll
        for (int t = 0; t < 4; t++) {
            uint lo = (uint)pu[t][0] | ((uint)pu[t][1] << 16);
            uint hi = (uint)pu[t][2] | ((uint)pu[t][3] << 16);
            *(uint*)(Pl + q16 * 72 + t * 16 + g * 4) = lo;
            *(uint*)(Pl + q16 * 72 + t * 16 + g * 4 + 2) = hi;
        }

        float al[4];
#pragma unroll
        for (int i = 0; i < 4; i++) al[i] = __shfl(alpha, g * 4 + i);
#pragma unroll
        for (int n = 0; n < 4; n++)
#pragma unroll
            for (int i = 0; i < 4; i++) ctxa[n][i] *= al[i];

        bf16x8 pa0 = *(const bf16x8*)(Pl + q16 * 72 + g * 8);
        bf16x8 pa1 = *(const bf16x8*)(Pl + q16 * 72 + g * 8 + 32);
#pragma unroll
        for (int n = 0; n < 4; n++) {
            const ushort* vr = Vbase + (size_t)(n * 16 + q16) * Seq + kv0;
            bf16x8 v0 = *(const bf16x8*)(vr + g * 8);
            bf16x8 v1 = *(const bf16x8*)(vr + g * 8 + 32);
            ctxa[n] = __builtin_amdgcn_mfma_f32_16x16x32_bf16(pa0, v0, ctxa[n], 0, 0, 0);
            ctxa[n] = __builtin_amdgcn_mfma_f32_16x16x32_bf16(pa1, v1, ctxa[n], 0, 0, 0);
        }
    }

    float rl = 1.f / l_run;
    float rli[4];
#pragma unroll
    for (int i = 0; i < 4; i++) rli[i] = __shfl(rl, g * 4 + i);
#pragma unroll
    for (int n = 0; n < 4; n++)
#pragma unroll
        for (int i = 0; i < 4; i++) {
            float v = ctxa[n][i] * rli[i];
            Ctx[(size_t)(b * Seq + qrow + g * 4 + i) * Dim + h * 64 + n * 16 + q16] = f2bf(v);
        }
}

extern "C" void kernel_launch(void* const* d_in, const int* in_sizes, int n_in,
                              void* d_out, int out_size, void* d_ws, size_t ws_size,
                              hipStream_t stream) {
    const float* X  = (const float*)d_in[0];
    const float* Wq = (const float*)d_in[1];
    const float* bq = (const float*)d_in[2];
    const float* Wk = (const float*)d_in[3];
    const float* bk = (const float*)d_in[4];
    const float* Wv = (const float*)d_in[5];
    const float* bv = (const float*)d_in[6];
    const float* Wo = (const float*)d_in[7];
    const float* bo = (const float*)d_in[8];

    char* ws = (char*)d_ws;
    ushort* Xb    = (ushort*)(ws);                      //  8 MB
    ushort* Wtqkv = (ushort*)(ws + 8388608);            //  6 MB
    ushort* Wto   = (ushort*)(ws + 14680064);           //  2 MB
    float*  bqkv  = (float*)(ws + 16777216);            // 12 KB
    ushort* QKVb  = (ushort*)(ws + 16793600);           // 24 MB
    ushort* VTb   = (ushort*)(ws + 41959424);           //  8 MB
    ushort* Ctxb  = (ushort*)(ws + 50348032);           //  8 MB

    convert_x<<<2048, 256, 0, stream>>>(X, Xb, Mtok * Dim / 8);
    dim3 tb(32, 8);
    transpose_w<<<dim3(32, 32), tb, 0, stream>>>(Wq, Wtqkv, 0.125f);
    transpose_w<<<dim3(32, 32), tb, 0, stream>>>(Wk, Wtqkv + 1024 * 1024, 1.f);
    transpose_w<<<dim3(32, 32), tb, 0, stream>>>(Wv, Wtqkv + 2 * 1024 * 1024, 1.f);
    transpose_w<<<dim3(32, 32), tb, 0, stream>>>(Wo, Wto, 1.f);
    concat_bias<<<12, 256, 0, stream>>>(bq, bk, bv, bqkv);

    gemm_bt<false><<<dim3(32, 24), 256, 0, stream>>>(Xb, Wtqkv, bqkv, QKVb, Mtok, NQKV, Dim);
    transpose_v<<<dim3(32, 32), 256, 0, stream>>>(QKVb, VTb);
    attn<<<dim3(32, 32), 256, 0, stream>>>(QKVb, VTb, Ctxb);
    gemm_bt<true><<<dim3(32, 8), 256, 0, stream>>>(Ctxb, Wto, bo, (float*)d_out, Mtok, Dim, Dim);
}

// Round 3
// 186.800 us; speedup vs baseline: 1.7192x; 1.7192x over previous
//
#include <hip/hip_runtime.h>
#include <hip/hip_bf16.h>
#include <cstdint>

constexpr int Bsz = 2, Seq = 2048, Dim = 1024, NH = 16, HDim = 64;
constexpr int Mtok = Bsz * Seq;           // 4096
constexpr int NQKV = 3 * Dim;             // 3072

typedef __attribute__((ext_vector_type(4))) float f32x4;
typedef __attribute__((ext_vector_type(8))) short bf16x8;

__device__ __forceinline__ ushort f2bf(float f) {
    union { float f; uint32_t u; } v; v.f = f;
    uint32_t u = v.u;
    uint32_t r = (u + 0x7fffu + ((u >> 16) & 1u)) >> 16;
    return (ushort)r;
}

__device__ __forceinline__ void gll16(const ushort* g, ushort* l) {
    __builtin_amdgcn_global_load_lds(
        (const __attribute__((address_space(1))) void*)g,
        (__attribute__((address_space(3))) void*)l, 16, 0, 0);
}

// ---------------- X fp32 -> bf16 ----------------
__global__ void convert_x(const float* __restrict__ in, ushort* __restrict__ out, int n8) {
    int i = blockIdx.x * 256 + threadIdx.x;
    if (i >= n8) return;
    const float4* p = (const float4*)in + (size_t)i * 2;
    float4 a = p[0], b = p[1];
    uint4 o;
    o.x = (uint)f2bf(a.x) | ((uint)f2bf(a.y) << 16);
    o.y = (uint)f2bf(a.z) | ((uint)f2bf(a.w) << 16);
    o.z = (uint)f2bf(b.x) | ((uint)f2bf(b.y) << 16);
    o.w = (uint)f2bf(b.z) | ((uint)f2bf(b.w) << 16);
    ((uint4*)out)[i] = o;
}

// ---------------- W [K][N] fp32 -> W^T [N][K] bf16 (with scale) ----------------
__global__ void transpose_w(const float* __restrict__ src, ushort* __restrict__ dst, float scale) {
    __shared__ float tile[32][33];
    int bx = blockIdx.x * 32, by = blockIdx.y * 32;
    int tx = threadIdx.x, ty = threadIdx.y;  // 32 x 8
#pragma unroll
    for (int j = 0; j < 32; j += 8)
        tile[ty + j][tx] = src[(size_t)(by + ty + j) * Dim + bx + tx];
    __syncthreads();
#pragma unroll
    for (int j = 0; j < 32; j += 8)
        dst[(size_t)(bx + ty + j) * Dim + by + tx] = f2bf(tile[tx][ty + j] * scale);
}

// ---------------- bias concat (bq*0.125, bk, bv) ----------------
__global__ void concat_bias(const float* __restrict__ bq, const float* __restrict__ bk,
                            const float* __restrict__ bv, float* __restrict__ dst) {
    int i = blockIdx.x * 256 + threadIdx.x;
    if (i >= NQKV) return;
    float v = (i < 1024) ? bq[i] * 0.125f : (i < 2048 ? bk[i - 1024] : bv[i - 2048]);
    dst[i] = v;
}

// ---------------- GEMM: C[M][N] = A[M][K]bf16 @ Bt[N][K]bf16^T + bias ----------------
template <bool F32OUT>
__global__ __launch_bounds__(256) void gemm_bt(const ushort* __restrict__ A,
                                               const ushort* __restrict__ Bt,
                                               const float* __restrict__ bias,
                                               void* __restrict__ Cout,
                                               int Msz, int Nsz, int Ksz) {
    __shared__ ushort As[128 * 32];
    __shared__ ushort Bs[128 * 32];
    const int tid = threadIdx.x;
    const int lane = tid & 63, wid = tid >> 6;
    const int wm = wid >> 1, wn = wid & 1;
    const int bm = blockIdx.x * 128, bn = blockIdx.y * 128;
    const int g = lane >> 4, r16 = lane & 15;

    f32x4 acc[4][4] = {};

    const int srow = tid >> 1;       // 0..127
    const int c0 = (tid & 1) * 2;    // chunk 0 or 2

    for (int k0 = 0; k0 < Ksz; k0 += 32) {
        __syncthreads();
        {
            const uint4* ga = (const uint4*)(A + (size_t)(bm + srow) * Ksz + k0);
            uint4 v0 = ga[c0], v1 = ga[c0 + 1];
            *(uint4*)(As + srow * 32 + ((c0 ^ (srow & 3)) * 8)) = v0;
            *(uint4*)(As + srow * 32 + (((c0 + 1) ^ (srow & 3)) * 8)) = v1;
            const uint4* gb = (const uint4*)(Bt + (size_t)(bn + srow) * Ksz + k0);
            uint4 w0 = gb[c0], w1 = gb[c0 + 1];
            *(uint4*)(Bs + srow * 32 + ((c0 ^ (srow & 3)) * 8)) = w0;
            *(uint4*)(Bs + srow * 32 + (((c0 + 1) ^ (srow & 3)) * 8)) = w1;
        }
        __syncthreads();
        bf16x8 af[4], bfr[4];
#pragma unroll
        for (int mt = 0; mt < 4; mt++) {
            int row = wm * 64 + mt * 16 + r16;
            af[mt] = *(const bf16x8*)(As + row * 32 + ((g ^ (row & 3)) * 8));
        }
#pragma unroll
        for (int nt = 0; nt < 4; nt++) {
            int row = wn * 64 + nt * 16 + r16;
            bfr[nt] = *(const bf16x8*)(Bs + row * 32 + ((g ^ (row & 3)) * 8));
        }
#pragma unroll
        for (int mt = 0; mt < 4; mt++)
#pragma unroll
            for (int nt = 0; nt < 4; nt++)
                acc[mt][nt] = __builtin_amdgcn_mfma_f32_16x16x32_bf16(af[mt], bfr[nt], acc[mt][nt], 0, 0, 0);
    }

#pragma unroll
    for (int nt = 0; nt < 4; nt++) {
        int col = bn + wn * 64 + nt * 16 + r16;
        float bv = bias[col];
#pragma unroll
        for (int mt = 0; mt < 4; mt++) {
            int row0 = bm + wm * 64 + mt * 16 + g * 4;
            f32x4 c = acc[mt][nt];
#pragma unroll
            for (int i = 0; i < 4; i++) {
                float v = c[i] + bv;
                if (F32OUT)
                    ((float*)Cout)[(size_t)(row0 + i) * Nsz + col] = v;
                else
                    ((ushort*)Cout)[(size_t)(row0 + i) * Nsz + col] = f2bf(v);
            }
        }
    }
}

// ---------------- pack K -> Kp[bh][s][d] (chunk-swizzled), V -> Vp[bh][tile][d][s] (chunk-swizzled)
// Both tile-contiguous 8KB so attn can stage them with linear global_load_lds.
// Swizzle: within each 128B row, 16B chunk c stored at physical chunk c ^ (row & 7).
__global__ __launch_bounds__(256) void pack_kv(const ushort* __restrict__ QKV,
                                               ushort* __restrict__ Kp,
                                               ushort* __restrict__ Vp) {
    __shared__ ushort t[64][72];
    int bh = blockIdx.y, b = bh >> 4, h = bh & 15;
    int s0 = blockIdx.x * 64;
    int tid = threadIdx.x;
    int r = tid >> 2, c = tid & 3;   // row 0..63, chunk 0..3 (and +4)
    // ---- K ----
    const ushort* ksrc = QKV + (size_t)(b * Seq + s0 + r) * NQKV + 1024 + h * 64;
    ushort* kdst = Kp + ((size_t)bh * Seq + s0 + r) * 64;
    int sw = r & 7;
    *(uint4*)(kdst + ((c ^ sw) * 8))       = *(const uint4*)(ksrc + c * 8);
    *(uint4*)(kdst + (((c + 4) ^ sw) * 8)) = *(const uint4*)(ksrc + (c + 4) * 8);
    // ---- V: load rows into LDS, transpose, write swizzled ----
    const ushort* vsrc = QKV + (size_t)(b * Seq + s0 + r) * NQKV + 2048 + h * 64;
    *(uint4*)(&t[r][c * 16])     = *(const uint4*)(vsrc + c * 16);
    *(uint4*)(&t[r][c * 16 + 8]) = *(const uint4*)(vsrc + c * 16 + 8);
    __syncthreads();
    int d = tid >> 2, cq = tid & 3;  // output row d, logical chunks cq*2, cq*2+1
    uint u[8];
#pragma unroll
    for (int jj = 0; jj < 8; jj++)
        u[jj] = (uint)t[cq * 16 + jj * 2][d] | ((uint)t[cq * 16 + jj * 2 + 1][d] << 16);
    int swd = d & 7;
    ushort* vdst = Vp + ((size_t)bh * Seq + s0) * 64 + d * 64;
    *(uint4*)(vdst + (((cq * 2) ^ swd) * 8))     = make_uint4(u[0], u[1], u[2], u[3]);
    *(uint4*)(vdst + (((cq * 2 + 1) ^ swd) * 8)) = make_uint4(u[4], u[5], u[6], u[7]);
}

// ---------------- flash attention ----------------
// grid (Seq/64, B*H), 256 thr = 4 waves (16 q-rows each), K/V tiles LDS-staged,
// double-buffered via global_load_lds from pre-swizzled Kp/Vp.
__global__ __launch_bounds__(256) void attn(const ushort* __restrict__ QKV,
                                            const ushort* __restrict__ Kp,
                                            const ushort* __restrict__ Vp,
                                            ushort* __restrict__ Ctx) {
    __shared__ ushort Ks[2][64 * 64];
    __shared__ ushort Vs[2][64 * 64];
    __shared__ ushort Plds[4][16 * 72];
    const int tid = threadIdx.x, lane = tid & 63, w = tid >> 6;
    const int bh = blockIdx.y, b = bh >> 4, h = bh & 15;
    const int g = lane >> 4, q16 = lane & 15;
    const int qrow = blockIdx.x * 64 + w * 16;

    const ushort* Qr = QKV + (size_t)(b * Seq + qrow + q16) * NQKV + h * 64;
    bf16x8 qf0 = *(const bf16x8*)(Qr + g * 8);
    bf16x8 qf1 = *(const bf16x8*)(Qr + g * 8 + 32);

    const ushort* KpB = Kp + (size_t)bh * Seq * 64;
    const ushort* VpB = Vp + (size_t)bh * Seq * 64;
    ushort* Pl = Plds[w];
    const int wb = w * 512;   // wave-uniform LDS chunk base (512 ushorts = 1KB)

#define STAGE(bufi, kv0_)  do {                                        \
        const ushort* ks_ = KpB + (size_t)(kv0_) * 64 + tid * 8;       \
        const ushort* vs_ = VpB + (size_t)(kv0_) * 64 + tid * 8;       \
        gll16(ks_,        &Ks[bufi][wb]);                              \
        gll16(ks_ + 2048, &Ks[bufi][2048 + wb]);                       \
        gll16(vs_,        &Vs[bufi][wb]);                              \
        gll16(vs_ + 2048, &Vs[bufi][2048 + wb]);                       \
    } while (0)

    STAGE(0, 0);

    f32x4 ctxa[4] = {};
    float m_run = -3.0e38f, l_run = 0.f;
    int cur = 0;
    const int swq = q16 & 7;

    for (int kv0 = 0; kv0 < Seq; kv0 += 64) {
        __syncthreads();   // drains vmcnt: buf[cur] staged; prev compute done
        if (kv0 + 64 < Seq) STAGE(cur ^ 1, kv0 + 64);
        const ushort* Kt = Ks[cur];
        const ushort* Vt = Vs[cur];

        f32x4 st[4] = {};
#pragma unroll
        for (int t = 0; t < 4; t++) {
            const ushort* kr = Kt + (t * 16 + q16) * 64;
            bf16x8 ka = *(const bf16x8*)(kr + ((g ^ swq) * 8));
            bf16x8 kb = *(const bf16x8*)(kr + (((g + 4) ^ swq) * 8));
            st[t] = __builtin_amdgcn_mfma_f32_16x16x32_bf16(ka, qf0, st[t], 0, 0, 0);
            st[t] = __builtin_amdgcn_mfma_f32_16x16x32_bf16(kb, qf1, st[t], 0, 0, 0);
        }
        float mloc = -3.0e38f;
#pragma unroll
        for (int t = 0; t < 4; t++)
#pragma unroll
            for (int i = 0; i < 4; i++) mloc = fmaxf(mloc, st[t][i]);
        mloc = fmaxf(mloc, __shfl_xor(mloc, 16));
        mloc = fmaxf(mloc, __shfl_xor(mloc, 32));
        float m_new = fmaxf(m_run, mloc);
        float alpha = __expf(m_run - m_new);

        float lsum = 0.f;
        ushort pu[4][4];
#pragma unroll
        for (int t = 0; t < 4; t++)
#pragma unroll
            for (int i = 0; i < 4; i++) {
                float p = __expf(st[t][i] - m_new);
                lsum += p;
                pu[t][i] = f2bf(p);
            }
        lsum += __shfl_xor(lsum, 16);
        lsum += __shfl_xor(lsum, 32);
        l_run = l_run * alpha + lsum;
        m_run = m_new;

#pragma unroll
        for (int t = 0; t < 4; t++) {
            uint lo = (uint)pu[t][0] | ((uint)pu[t][1] << 16);
            uint hi = (uint)pu[t][2] | ((uint)pu[t][3] << 16);
            *(uint*)(Pl + q16 * 72 + t * 16 + g * 4) = lo;
            *(uint*)(Pl + q16 * 72 + t * 16 + g * 4 + 2) = hi;
        }

        float al[4];
#pragma unroll
        for (int i = 0; i < 4; i++) al[i] = __shfl(alpha, g * 4 + i);
#pragma unroll
        for (int n = 0; n < 4; n++)
#pragma unroll
            for (int i = 0; i < 4; i++) ctxa[n][i] *= al[i];

        bf16x8 pa0 = *(const bf16x8*)(Pl + q16 * 72 + g * 8);
        bf16x8 pa1 = *(const bf16x8*)(Pl + q16 * 72 + g * 8 + 32);
#pragma unroll
        for (int n = 0; n < 4; n++) {
            const ushort* vr = Vt + (n * 16 + q16) * 64;
            bf16x8 v0 = *(const bf16x8*)(vr + ((g ^ swq) * 8));
            bf16x8 v1 = *(const bf16x8*)(vr + (((g + 4) ^ swq) * 8));
            ctxa[n] = __builtin_amdgcn_mfma_f32_16x16x32_bf16(pa0, v0, ctxa[n], 0, 0, 0);
            ctxa[n] = __builtin_amdgcn_mfma_f32_16x16x32_bf16(pa1, v1, ctxa[n], 0, 0, 0);
        }
        cur ^= 1;
    }
#undef STAGE

    float rl = 1.f / l_run;
    float rli[4];
#pragma unroll
    for (int i = 0; i < 4; i++) rli[i] = __shfl(rl, g * 4 + i);
#pragma unroll
    for (int n = 0; n < 4; n++)
#pragma unroll
        for (int i = 0; i < 4; i++) {
            float v = ctxa[n][i] * rli[i];
            Ctx[(size_t)(b * Seq + qrow + g * 4 + i) * Dim + h * 64 + n * 16 + q16] = f2bf(v);
        }
}

extern "C" void kernel_launch(void* const* d_in, const int* in_sizes, int n_in,
                              void* d_out, int out_size, void* d_ws, size_t ws_size,
                              hipStream_t stream) {
    const float* X  = (const float*)d_in[0];
    const float* Wq = (const float*)d_in[1];
    const float* bq = (const float*)d_in[2];
    const float* Wk = (const float*)d_in[3];
    const float* bk = (const float*)d_in[4];
    const float* Wv = (const float*)d_in[5];
    const float* bv = (const float*)d_in[6];
    const float* Wo = (const float*)d_in[7];
    const float* bo = (const float*)d_in[8];

    char* ws = (char*)d_ws;
    ushort* Xb    = (ushort*)(ws);                      //  8 MB (reused as Kp after QKV GEMM)
    ushort* Wtqkv = (ushort*)(ws + 8388608);            //  6 MB
    ushort* Wto   = (ushort*)(ws + 14680064);           //  2 MB
    float*  bqkv  = (float*)(ws + 16777216);            // 12 KB
    ushort* QKVb  = (ushort*)(ws + 16793600);           // 24 MB
    ushort* Vp    = (ushort*)(ws + 41959424);           //  8 MB
    ushort* Ctxb  = (ushort*)(ws + 50348032);           //  8 MB
    ushort* Kp    = Xb;                                 // alias: Xb dead after QKV GEMM

    convert_x<<<2048, 256, 0, stream>>>(X, Xb, Mtok * Dim / 8);
    dim3 tb(32, 8);
    transpose_w<<<dim3(32, 32), tb, 0, stream>>>(Wq, Wtqkv, 0.125f);
    transpose_w<<<dim3(32, 32), tb, 0, stream>>>(Wk, Wtqkv + 1024 * 1024, 1.f);
    transpose_w<<<dim3(32, 32), tb, 0, stream>>>(Wv, Wtqkv + 2 * 1024 * 1024, 1.f);
    transpose_w<<<dim3(32, 32), tb, 0, stream>>>(Wo, Wto, 1.f);
    concat_bias<<<12, 256, 0, stream>>>(bq, bk, bv, bqkv);

    gemm_bt<false><<<dim3(32, 24), 256, 0, stream>>>(Xb, Wtqkv, bqkv, QKVb, Mtok, NQKV, Dim);
    pack_kv<<<dim3(32, 32), 256, 0, stream>>>(QKVb, Kp, Vp);
    attn<<<dim3(32, 32), 256, 0, stream>>>(QKVb, Kp, Vp, Ctxb);
    gemm_bt<true><<<dim3(32, 8), 256, 0, stream>>>(Ctxb, Wto, bo, (float*)d_out, Mtok, Dim, Dim);
}

// Round 4
// 173.071 us; speedup vs baseline: 1.8556x; 1.0793x over previous
//
#include <hip/hip_runtime.h>
#include <hip/hip_bf16.h>
#include <cstdint>

constexpr int Bsz = 2, Seq = 2048, Dim = 1024, NH = 16, HDim = 64;
constexpr int Mtok = Bsz * Seq;           // 4096
constexpr int NQKV = 3 * Dim;             // 3072
constexpr float QSCALE = 0.125f * 1.4426950408889634f;  // 1/sqrt(64) * log2(e)

typedef __attribute__((ext_vector_type(4))) float f32x4;
typedef __attribute__((ext_vector_type(8))) short bf16x8;

#if __has_builtin(__builtin_amdgcn_exp2f)
#define EXP2(x) __builtin_amdgcn_exp2f(x)
#else
#define EXP2(x) exp2f(x)
#endif

__device__ __forceinline__ ushort f2bf(float f) {
    union { float f; uint32_t u; } v; v.f = f;
    uint32_t u = v.u;
    uint32_t r = (u + 0x7fffu + ((u >> 16) & 1u)) >> 16;
    return (ushort)r;
}

__device__ __forceinline__ uint cvt_pk_bf16(float lo, float hi) {
    uint r;
    asm("v_cvt_pk_bf16_f32 %0, %1, %2" : "=v"(r) : "v"(lo), "v"(hi));
    return r;
}

__device__ __forceinline__ void gll16(const ushort* g, ushort* l) {
    __builtin_amdgcn_global_load_lds(
        (const __attribute__((address_space(1))) void*)g,
        (__attribute__((address_space(3))) void*)l, 16, 0, 0);
}

// ---------------- X fp32 -> bf16 ----------------
__global__ void convert_x(const float* __restrict__ in, ushort* __restrict__ out, int n8) {
    int i = blockIdx.x * 256 + threadIdx.x;
    if (i >= n8) return;
    const float4* p = (const float4*)in + (size_t)i * 2;
    float4 a = p[0], b = p[1];
    uint4 o;
    o.x = (uint)f2bf(a.x) | ((uint)f2bf(a.y) << 16);
    o.y = (uint)f2bf(a.z) | ((uint)f2bf(a.w) << 16);
    o.z = (uint)f2bf(b.x) | ((uint)f2bf(b.y) << 16);
    o.w = (uint)f2bf(b.z) | ((uint)f2bf(b.w) << 16);
    ((uint4*)out)[i] = o;
}

// ---------------- W [K][N] fp32 -> W^T [N][K] bf16 (with scale) ----------------
__global__ void transpose_w(const float* __restrict__ src, ushort* __restrict__ dst, float scale) {
    __shared__ float tile[32][33];
    int bx = blockIdx.x * 32, by = blockIdx.y * 32;
    int tx = threadIdx.x, ty = threadIdx.y;  // 32 x 8
#pragma unroll
    for (int j = 0; j < 32; j += 8)
        tile[ty + j][tx] = src[(size_t)(by + ty + j) * Dim + bx + tx];
    __syncthreads();
#pragma unroll
    for (int j = 0; j < 32; j += 8)
        dst[(size_t)(bx + ty + j) * Dim + by + tx] = f2bf(tile[tx][ty + j] * scale);
}

// ---------------- bias concat (bq*QSCALE, bk, bv) ----------------
__global__ void concat_bias(const float* __restrict__ bq, const float* __restrict__ bk,
                            const float* __restrict__ bv, float* __restrict__ dst) {
    int i = blockIdx.x * 256 + threadIdx.x;
    if (i >= NQKV) return;
    float v = (i < 1024) ? bq[i] * QSCALE : (i < 2048 ? bk[i - 1024] : bv[i - 2048]);
    dst[i] = v;
}

// ---------------- GEMM: C[M][N] = A[M][K]bf16 @ Bt[N][K]bf16^T + bias ----------------
template <bool F32OUT>
__global__ __launch_bounds__(256) void gemm_bt(const ushort* __restrict__ A,
                                               const ushort* __restrict__ Bt,
                                               const float* __restrict__ bias,
                                               void* __restrict__ Cout,
                                               int Msz, int Nsz, int Ksz) {
    __shared__ ushort As[128 * 32];
    __shared__ ushort Bs[128 * 32];
    const int tid = threadIdx.x;
    const int lane = tid & 63, wid = tid >> 6;
    const int wm = wid >> 1, wn = wid & 1;
    const int bm = blockIdx.x * 128, bn = blockIdx.y * 128;
    const int g = lane >> 4, r16 = lane & 15;

    f32x4 acc[4][4] = {};

    const int srow = tid >> 1;       // 0..127
    const int c0 = (tid & 1) * 2;    // chunk 0 or 2

    for (int k0 = 0; k0 < Ksz; k0 += 32) {
        __syncthreads();
        {
            const uint4* ga = (const uint4*)(A + (size_t)(bm + srow) * Ksz + k0);
            uint4 v0 = ga[c0], v1 = ga[c0 + 1];
            *(uint4*)(As + srow * 32 + ((c0 ^ (srow & 3)) * 8)) = v0;
            *(uint4*)(As + srow * 32 + (((c0 + 1) ^ (srow & 3)) * 8)) = v1;
            const uint4* gb = (const uint4*)(Bt + (size_t)(bn + srow) * Ksz + k0);
            uint4 w0 = gb[c0], w1 = gb[c0 + 1];
            *(uint4*)(Bs + srow * 32 + ((c0 ^ (srow & 3)) * 8)) = w0;
            *(uint4*)(Bs + srow * 32 + (((c0 + 1) ^ (srow & 3)) * 8)) = w1;
        }
        __syncthreads();
        bf16x8 af[4], bfr[4];
#pragma unroll
        for (int mt = 0; mt < 4; mt++) {
            int row = wm * 64 + mt * 16 + r16;
            af[mt] = *(const bf16x8*)(As + row * 32 + ((g ^ (row & 3)) * 8));
        }
#pragma unroll
        for (int nt = 0; nt < 4; nt++) {
            int row = wn * 64 + nt * 16 + r16;
            bfr[nt] = *(const bf16x8*)(Bs + row * 32 + ((g ^ (row & 3)) * 8));
        }
#pragma unroll
        for (int mt = 0; mt < 4; mt++)
#pragma unroll
            for (int nt = 0; nt < 4; nt++)
                acc[mt][nt] = __builtin_amdgcn_mfma_f32_16x16x32_bf16(af[mt], bfr[nt], acc[mt][nt], 0, 0, 0);
    }

#pragma unroll
    for (int nt = 0; nt < 4; nt++) {
        int col = bn + wn * 64 + nt * 16 + r16;
        float bv = bias[col];
#pragma unroll
        for (int mt = 0; mt < 4; mt++) {
            int row0 = bm + wm * 64 + mt * 16 + g * 4;
            f32x4 c = acc[mt][nt];
#pragma unroll
            for (int i = 0; i < 4; i++) {
                float v = c[i] + bv;
                if (F32OUT)
                    ((float*)Cout)[(size_t)(row0 + i) * Nsz + col] = v;
                else
                    ((ushort*)Cout)[(size_t)(row0 + i) * Nsz + col] = f2bf(v);
            }
        }
    }
}

// ---------------- pack K -> Kp[bh][s][d] (chunk-swizzled), V -> Vp[bh][tile][d][s] (chunk-swizzled)
__global__ __launch_bounds__(256) void pack_kv(const ushort* __restrict__ QKV,
                                               ushort* __restrict__ Kp,
                                               ushort* __restrict__ Vp) {
    __shared__ ushort t[64][72];
    int bh = blockIdx.y, b = bh >> 4, h = bh & 15;
    int s0 = blockIdx.x * 64;
    int tid = threadIdx.x;
    int r = tid >> 2, c = tid & 3;   // row 0..63, chunk 0..3 (and +4)
    // ---- K ----
    const ushort* ksrc = QKV + (size_t)(b * Seq + s0 + r) * NQKV + 1024 + h * 64;
    ushort* kdst = Kp + ((size_t)bh * Seq + s0 + r) * 64;
    int sw = r & 7;
    *(uint4*)(kdst + ((c ^ sw) * 8))       = *(const uint4*)(ksrc + c * 8);
    *(uint4*)(kdst + (((c + 4) ^ sw) * 8)) = *(const uint4*)(ksrc + (c + 4) * 8);
    // ---- V: load rows into LDS, transpose, write swizzled ----
    const ushort* vsrc = QKV + (size_t)(b * Seq + s0 + r) * NQKV + 2048 + h * 64;
    *(uint4*)(&t[r][c * 16])     = *(const uint4*)(vsrc + c * 16);
    *(uint4*)(&t[r][c * 16 + 8]) = *(const uint4*)(vsrc + c * 16 + 8);
    __syncthreads();
    int d = tid >> 2, cq = tid & 3;  // output row d, logical chunks cq*2, cq*2+1
    uint u[8];
#pragma unroll
    for (int jj = 0; jj < 8; jj++)
        u[jj] = (uint)t[cq * 16 + jj * 2][d] | ((uint)t[cq * 16 + jj * 2 + 1][d] << 16);
    int swd = d & 7;
    ushort* vdst = Vp + ((size_t)bh * Seq + s0) * 64 + d * 64;
    *(uint4*)(vdst + (((cq * 2) ^ swd) * 8))     = make_uint4(u[0], u[1], u[2], u[3]);
    *(uint4*)(vdst + (((cq * 2 + 1) ^ swd) * 8)) = make_uint4(u[4], u[5], u[6], u[7]);
}

// ---------------- flash attention ----------------
__global__ __launch_bounds__(256) void attn(const ushort* __restrict__ QKV,
                                            const ushort* __restrict__ Kp,
                                            const ushort* __restrict__ Vp,
                                            ushort* __restrict__ Ctx) {
    __shared__ ushort Ks[2][64 * 64];
    __shared__ ushort Vs[2][64 * 64];
    __shared__ ushort Plds[4][16 * 72];
    const int tid = threadIdx.x, lane = tid & 63, w = tid >> 6;
    const int bh = blockIdx.y, b = bh >> 4, h = bh & 15;
    const int g = lane >> 4, q16 = lane & 15;
    const int qrow = blockIdx.x * 64 + w * 16;

    const ushort* Qr = QKV + (size_t)(b * Seq + qrow + q16) * NQKV + h * 64;
    bf16x8 qf0 = *(const bf16x8*)(Qr + g * 8);
    bf16x8 qf1 = *(const bf16x8*)(Qr + g * 8 + 32);

    const ushort* KpB = Kp + (size_t)bh * Seq * 64;
    const ushort* VpB = Vp + (size_t)bh * Seq * 64;
    ushort* Pl = Plds[w];
    const int wb = w * 512;   // wave-uniform LDS chunk base (512 ushorts = 1KB)

#define STAGE(bufi, kv0_)  do {                                        \
        const ushort* ks_ = KpB + (size_t)(kv0_) * 64 + tid * 8;       \
        const ushort* vs_ = VpB + (size_t)(kv0_) * 64 + tid * 8;       \
        gll16(ks_,        &Ks[bufi][wb]);                              \
        gll16(ks_ + 2048, &Ks[bufi][2048 + wb]);                       \
        gll16(vs_,        &Vs[bufi][wb]);                              \
        gll16(vs_ + 2048, &Vs[bufi][2048 + wb]);                       \
    } while (0)

    STAGE(0, 0);

    f32x4 ctxa[4] = {};
    float m_run = -3.0e38f, l_run = 0.f;
    int cur = 0;
    const int swq = q16 & 7;

    for (int kv0 = 0; kv0 < Seq; kv0 += 64) {
        __syncthreads();   // drains vmcnt: buf[cur] staged; prev compute done
        if (kv0 + 64 < Seq) STAGE(cur ^ 1, kv0 + 64);
        const ushort* Kt = Ks[cur];
        const ushort* Vt = Vs[cur];

        f32x4 st[4] = {};
#pragma unroll
        for (int t = 0; t < 4; t++) {
            const ushort* kr = Kt + (t * 16 + q16) * 64;
            bf16x8 ka = *(const bf16x8*)(kr + ((g ^ swq) * 8));
            bf16x8 kb = *(const bf16x8*)(kr + (((g + 4) ^ swq) * 8));
            st[t] = __builtin_amdgcn_mfma_f32_16x16x32_bf16(ka, qf0, st[t], 0, 0, 0);
            st[t] = __builtin_amdgcn_mfma_f32_16x16x32_bf16(kb, qf1, st[t], 0, 0, 0);
        }
        // wave-reduced tile max (uniform across the 4 g-groups of each q16)
        float mloc = fmaxf(fmaxf(fmaxf(st[0][0], st[0][1]), fmaxf(st[0][2], st[0][3])),
                           fmaxf(fmaxf(st[1][0], st[1][1]), fmaxf(st[1][2], st[1][3])));
        mloc = fmaxf(mloc,
               fmaxf(fmaxf(fmaxf(st[2][0], st[2][1]), fmaxf(st[2][2], st[2][3])),
                     fmaxf(fmaxf(st[3][0], st[3][1]), fmaxf(st[3][2], st[3][3]))));
        mloc = fmaxf(mloc, __shfl_xor(mloc, 16));
        mloc = fmaxf(mloc, __shfl_xor(mloc, 32));

        // defer-max (T13): only rescale when max grew past threshold (log2 domain)
        if (__any(mloc > m_run + 8.f)) {
            float m_new = fmaxf(m_run, mloc);
            float alpha = EXP2(m_run - m_new);
            float al[4];
#pragma unroll
            for (int i = 0; i < 4; i++) al[i] = __shfl(alpha, g * 4 + i);
#pragma unroll
            for (int n = 0; n < 4; n++)
#pragma unroll
                for (int i = 0; i < 4; i++) ctxa[n][i] *= al[i];
            l_run *= alpha;
            m_run = m_new;
        }

        float lsum = 0.f;
#pragma unroll
        for (int t = 0; t < 4; t++) {
            float p0 = EXP2(st[t][0] - m_run);
            float p1 = EXP2(st[t][1] - m_run);
            float p2 = EXP2(st[t][2] - m_run);
            float p3 = EXP2(st[t][3] - m_run);
            lsum += (p0 + p1) + (p2 + p3);
            uint2 pk;
            pk.x = cvt_pk_bf16(p0, p1);
            pk.y = cvt_pk_bf16(p2, p3);
            *(uint2*)(Pl + q16 * 72 + t * 16 + g * 4) = pk;   // byte ofs 8-aligned
        }
        l_run += lsum;   // per-lane partial; cross-lane reduce deferred to end

        bf16x8 pa0 = *(const bf16x8*)(Pl + q16 * 72 + g * 8);
        bf16x8 pa1 = *(const bf16x8*)(Pl + q16 * 72 + g * 8 + 32);
#pragma unroll
        for (int n = 0; n < 4; n++) {
            const ushort* vr = Vt + (n * 16 + q16) * 64;
            bf16x8 v0 = *(const bf16x8*)(vr + ((g ^ swq) * 8));
            bf16x8 v1 = *(const bf16x8*)(vr + (((g + 4) ^ swq) * 8));
            ctxa[n] = __builtin_amdgcn_mfma_f32_16x16x32_bf16(pa0, v0, ctxa[n], 0, 0, 0);
            ctxa[n] = __builtin_amdgcn_mfma_f32_16x16x32_bf16(pa1, v1, ctxa[n], 0, 0, 0);
        }
        cur ^= 1;
    }
#undef STAGE

    // finish the deferred l reduction (alpha scaling commuted: uniform per q16)
    l_run += __shfl_xor(l_run, 16);
    l_run += __shfl_xor(l_run, 32);
    float rl = 1.f / l_run;
    float rli[4];
#pragma unroll
    for (int i = 0; i < 4; i++) rli[i] = __shfl(rl, g * 4 + i);
#pragma unroll
    for (int n = 0; n < 4; n++)
#pragma unroll
        for (int i = 0; i < 4; i++) {
            float v = ctxa[n][i] * rli[i];
            Ctx[(size_t)(b * Seq + qrow + g * 4 + i) * Dim + h * 64 + n * 16 + q16] = f2bf(v);
        }
}

extern "C" void kernel_launch(void* const* d_in, const int* in_sizes, int n_in,
                              void* d_out, int out_size, void* d_ws, size_t ws_size,
                              hipStream_t stream) {
    const float* X  = (const float*)d_in[0];
    const float* Wq = (const float*)d_in[1];
    const float* bq = (const float*)d_in[2];
    const float* Wk = (const float*)d_in[3];
    const float* bk = (const float*)d_in[4];
    const float* Wv = (const float*)d_in[5];
    const float* bv = (const float*)d_in[6];
    const float* Wo = (const float*)d_in[7];
    const float* bo = (const float*)d_in[8];

    char* ws = (char*)d_ws;
    ushort* Xb    = (ushort*)(ws);                      //  8 MB (reused as Kp after QKV GEMM)
    ushort* Wtqkv = (ushort*)(ws + 8388608);            //  6 MB
    ushort* Wto   = (ushort*)(ws + 14680064);           //  2 MB
    float*  bqkv  = (float*)(ws + 16777216);            // 12 KB
    ushort* QKVb  = (ushort*)(ws + 16793600);           // 24 MB
    ushort* Vp    = (ushort*)(ws + 41959424);           //  8 MB
    ushort* Ctxb  = (ushort*)(ws + 50348032);           //  8 MB
    ushort* Kp    = Xb;                                 // alias: Xb dead after QKV GEMM

    convert_x<<<2048, 256, 0, stream>>>(X, Xb, Mtok * Dim / 8);
    dim3 tb(32, 8);
    transpose_w<<<dim3(32, 32), tb, 0, stream>>>(Wq, Wtqkv, QSCALE);
    transpose_w<<<dim3(32, 32), tb, 0, stream>>>(Wk, Wtqkv + 1024 * 1024, 1.f);
    transpose_w<<<dim3(32, 32), tb, 0, stream>>>(Wv, Wtqkv + 2 * 1024 * 1024, 1.f);
    transpose_w<<<dim3(32, 32), tb, 0, stream>>>(Wo, Wto, 1.f);
    concat_bias<<<12, 256, 0, stream>>>(bq, bk, bv, bqkv);

    gemm_bt<false><<<dim3(32, 24), 256, 0, stream>>>(Xb, Wtqkv, bqkv, QKVb, Mtok, NQKV, Dim);
    pack_kv<<<dim3(32, 32), 256, 0, stream>>>(QKVb, Kp, Vp);
    attn<<<dim3(32, 32), 256, 0, stream>>>(QKVb, Kp, Vp, Ctxb);
    gemm_bt<true><<<dim3(32, 8), 256, 0, stream>>>(Ctxb, Wto, bo, (float*)d_out, Mtok, Dim, Dim);
}

// Round 5
// 154.046 us; speedup vs baseline: 2.0847x; 1.1235x over previous
//
#include <hip/hip_runtime.h>
#include <hip/hip_bf16.h>
#include <cstdint>

constexpr int Bsz = 2, Seq = 2048, Dim = 1024, NH = 16, HDim = 64;
constexpr int Mtok = Bsz * Seq;           // 4096
constexpr int NQKV = 3 * Dim;             // 3072
constexpr float QSCALE = 0.125f * 1.4426950408889634f;  // 1/sqrt(64) * log2(e)

typedef __attribute__((ext_vector_type(4))) float f32x4;
typedef __attribute__((ext_vector_type(8))) short bf16x8;

#if __has_builtin(__builtin_amdgcn_exp2f)
#define EXP2(x) __builtin_amdgcn_exp2f(x)
#else
#define EXP2(x) exp2f(x)
#endif

__device__ __forceinline__ ushort f2bf(float f) {
    union { float f; uint32_t u; } v; v.f = f;
    uint32_t u = v.u;
    uint32_t r = (u + 0x7fffu + ((u >> 16) & 1u)) >> 16;
    return (ushort)r;
}

__device__ __forceinline__ uint cvt_pk_bf16(float lo, float hi) {
    uint r;
    asm("v_cvt_pk_bf16_f32 %0, %1, %2" : "=v"(r) : "v"(lo), "v"(hi));
    return r;
}

__device__ __forceinline__ void gll16(const ushort* g, ushort* l) {
    __builtin_amdgcn_global_load_lds(
        (const __attribute__((address_space(1))) void*)g,
        (__attribute__((address_space(3))) void*)l, 16, 0, 0);
}

__device__ __forceinline__ float rmax4(f32x4 v) {
    return fmaxf(fmaxf(v[0], v[1]), fmaxf(v[2], v[3]));
}

// ---------------- X fp32 -> bf16, chunk-swizzled for gemm A staging ----------------
// Within each 32-elem K-block of a row: 16B chunk c stored at c ^ (row & 3).
__global__ void convert_x(const float* __restrict__ in, ushort* __restrict__ out, int n16) {
    int i = blockIdx.x * 256 + threadIdx.x;
    if (i >= n16) return;
    int e = i * 16;
    int row = e >> 10;
    int k = e & 1023;            // multiple of 16
    int k0 = k & ~31;
    int c = (k >> 3) & 3;        // 0 or 2
    int sw = row & 3;
    const float4* p = (const float4*)(in + e);
    float4 a = p[0], b = p[1], c2 = p[2], d = p[3];
    uint4 o0, o1;
    o0.x = (uint)f2bf(a.x) | ((uint)f2bf(a.y) << 16);
    o0.y = (uint)f2bf(a.z) | ((uint)f2bf(a.w) << 16);
    o0.z = (uint)f2bf(b.x) | ((uint)f2bf(b.y) << 16);
    o0.w = (uint)f2bf(b.z) | ((uint)f2bf(b.w) << 16);
    o1.x = (uint)f2bf(c2.x) | ((uint)f2bf(c2.y) << 16);
    o1.y = (uint)f2bf(c2.z) | ((uint)f2bf(c2.w) << 16);
    o1.z = (uint)f2bf(d.x) | ((uint)f2bf(d.y) << 16);
    o1.w = (uint)f2bf(d.z) | ((uint)f2bf(d.w) << 16);
    ushort* dstrow = out + (size_t)row * 1024 + k0;
    *(uint4*)(dstrow + ((c ^ sw) << 3))       = o0;
    *(uint4*)(dstrow + (((c + 1) ^ sw) << 3)) = o1;
}

// ---------------- W [K][N] fp32 -> W^T [N][K] bf16 (scaled, chunk-swizzled) ----------------
__global__ void transpose_w(const float* __restrict__ src, ushort* __restrict__ dst, float scale) {
    __shared__ float tile[32][33];
    int bx = blockIdx.x * 32, by = blockIdx.y * 32;
    int tx = threadIdx.x, ty = threadIdx.y;  // 32 x 8
#pragma unroll
    for (int j = 0; j < 32; j += 8)
        tile[ty + j][tx] = src[(size_t)(by + ty + j) * Dim + bx + tx];
    __syncthreads();
    int c = tx >> 3, wn8 = tx & 7;
#pragma unroll
    for (int j = 0; j < 32; j += 8) {
        int n = bx + ty + j;
        dst[(size_t)n * Dim + by + ((c ^ (n & 3)) << 3) + wn8] = f2bf(tile[tx][ty + j] * scale);
    }
}

// ---------------- bias concat (bq*QSCALE, bk, bv) ----------------
__global__ void concat_bias(const float* __restrict__ bq, const float* __restrict__ bk,
                            const float* __restrict__ bv, float* __restrict__ dst) {
    int i = blockIdx.x * 256 + threadIdx.x;
    if (i >= NQKV) return;
    float v = (i < 1024) ? bq[i] * QSCALE : (i < 2048 ? bk[i - 1024] : bv[i - 2048]);
    dst[i] = v;
}

// ---------------- GEMM: C[M][N] = A[M][K]bf16 @ Bt[N][K]bf16^T + bias ----------------
// A and Bt are chunk-PRE-SWIZZLED in global; staging via global_load_lds (linear dest).
template <bool F32OUT>
__global__ __launch_bounds__(256) void gemm_bt(const ushort* __restrict__ A,
                                               const ushort* __restrict__ Bt,
                                               const float* __restrict__ bias,
                                               void* __restrict__ Cout,
                                               int Msz, int Nsz, int Ksz) {
    __shared__ ushort As[128 * 32];
    __shared__ ushort Bs[128 * 32];
    const int tid = threadIdx.x;
    const int lane = tid & 63, wid = tid >> 6;
    const int wm = wid >> 1, wn = wid & 1;
    const int bm = blockIdx.x * 128, bn = blockIdx.y * 128;
    const int g = lane >> 4, r16 = lane & 15;

    f32x4 acc[4][4] = {};

    const int srow = tid >> 2;   // 0..63
    const int sc = tid & 3;      // chunk 0..3
    const ushort* ga0 = A + (size_t)(bm + srow) * Ksz + sc * 8;
    const ushort* ga1 = A + (size_t)(bm + 64 + srow) * Ksz + sc * 8;
    const ushort* gb0 = Bt + (size_t)(bn + srow) * Ksz + sc * 8;
    const ushort* gb1 = Bt + (size_t)(bn + 64 + srow) * Ksz + sc * 8;
    ushort* la0 = As + (wid << 9);
    ushort* la1 = As + 2048 + (wid << 9);
    ushort* lb0 = Bs + (wid << 9);
    ushort* lb1 = Bs + 2048 + (wid << 9);

    for (int k0 = 0; k0 < Ksz; k0 += 32) {
        __syncthreads();          // prev iter's LDS reads done
        gll16(ga0 + k0, la0);
        gll16(ga1 + k0, la1);
        gll16(gb0 + k0, lb0);
        gll16(gb1 + k0, lb1);
        __syncthreads();          // drains vmcnt: tile resident
        bf16x8 af[4], bfr[4];
#pragma unroll
        for (int mt = 0; mt < 4; mt++) {
            int row = wm * 64 + mt * 16 + r16;
            af[mt] = *(const bf16x8*)(As + row * 32 + ((g ^ (row & 3)) * 8));
        }
#pragma unroll
        for (int nt = 0; nt < 4; nt++) {
            int row = wn * 64 + nt * 16 + r16;
            bfr[nt] = *(const bf16x8*)(Bs + row * 32 + ((g ^ (row & 3)) * 8));
        }
#pragma unroll
        for (int mt = 0; mt < 4; mt++)
#pragma unroll
            for (int nt = 0; nt < 4; nt++)
                acc[mt][nt] = __builtin_amdgcn_mfma_f32_16x16x32_bf16(af[mt], bfr[nt], acc[mt][nt], 0, 0, 0);
    }

#pragma unroll
    for (int nt = 0; nt < 4; nt++) {
        int col = bn + wn * 64 + nt * 16 + r16;
        float bv = bias[col];
#pragma unroll
        for (int mt = 0; mt < 4; mt++) {
            int row0 = bm + wm * 64 + mt * 16 + g * 4;
            f32x4 c = acc[mt][nt];
#pragma unroll
            for (int i = 0; i < 4; i++) {
                float v = c[i] + bv;
                if (F32OUT)
                    ((float*)Cout)[(size_t)(row0 + i) * Nsz + col] = v;
                else
                    ((ushort*)Cout)[(size_t)(row0 + i) * Nsz + col] = f2bf(v);
            }
        }
    }
}

// ---------------- pack K -> Kp[bh][s][d], V -> Vp[bh][tile][d][s] (both 16B-chunk swizzled) ----------------
__global__ __launch_bounds__(256) void pack_kv(const ushort* __restrict__ QKV,
                                               ushort* __restrict__ Kp,
                                               ushort* __restrict__ Vp) {
    __shared__ ushort t[64][72];
    int bh = blockIdx.y, b = bh >> 4, h = bh & 15;
    int s0 = blockIdx.x * 64;
    int tid = threadIdx.x;
    int r = tid >> 2, c = tid & 3;
    // ---- K ----
    const ushort* ksrc = QKV + (size_t)(b * Seq + s0 + r) * NQKV + 1024 + h * 64;
    ushort* kdst = Kp + ((size_t)bh * Seq + s0 + r) * 64;
    int sw = r & 7;
    *(uint4*)(kdst + ((c ^ sw) * 8))       = *(const uint4*)(ksrc + c * 8);
    *(uint4*)(kdst + (((c + 4) ^ sw) * 8)) = *(const uint4*)(ksrc + (c + 4) * 8);
    // ---- V transpose ----
    const ushort* vsrc = QKV + (size_t)(b * Seq + s0 + r) * NQKV + 2048 + h * 64;
    *(uint4*)(&t[r][c * 16])     = *(const uint4*)(vsrc + c * 16);
    *(uint4*)(&t[r][c * 16 + 8]) = *(const uint4*)(vsrc + c * 16 + 8);
    __syncthreads();
    int d = tid >> 2, cq = tid & 3;
    uint u[8];
#pragma unroll
    for (int jj = 0; jj < 8; jj++)
        u[jj] = (uint)t[cq * 16 + jj * 2][d] | ((uint)t[cq * 16 + jj * 2 + 1][d] << 16);
    int swd = d & 7;
    ushort* vdst = Vp + ((size_t)bh * Seq + s0) * 64 + d * 64;
    *(uint4*)(vdst + (((cq * 2) ^ swd) * 8))     = make_uint4(u[0], u[1], u[2], u[3]);
    *(uint4*)(vdst + (((cq * 2 + 1) ^ swd) * 8)) = make_uint4(u[4], u[5], u[6], u[7]);
}

// ---------------- flash attention: 4 waves x 32 q-rows = 128 q/block ----------------
__global__ __launch_bounds__(256) void attn(const ushort* __restrict__ QKV,
                                            const ushort* __restrict__ Kp,
                                            const ushort* __restrict__ Vp,
                                            ushort* __restrict__ Ctx) {
    __shared__ ushort Ks[2][64 * 64];
    __shared__ ushort Vs[2][64 * 64];
    __shared__ ushort Plds[4][32 * 72];
    const int tid = threadIdx.x, lane = tid & 63, w = tid >> 6;
    const int bh = blockIdx.y, b = bh >> 4, h = bh & 15;
    const int g = lane >> 4, q16 = lane & 15;
    const int qrow = blockIdx.x * 128 + w * 32;

    const ushort* QrA = QKV + (size_t)(b * Seq + qrow + q16) * NQKV + h * 64;
    const ushort* QrB = QrA + (size_t)16 * NQKV;
    bf16x8 qa0 = *(const bf16x8*)(QrA + g * 8);
    bf16x8 qa1 = *(const bf16x8*)(QrA + g * 8 + 32);
    bf16x8 qb0 = *(const bf16x8*)(QrB + g * 8);
    bf16x8 qb1 = *(const bf16x8*)(QrB + g * 8 + 32);

    const ushort* KpB = Kp + (size_t)bh * Seq * 64;
    const ushort* VpB = Vp + (size_t)bh * Seq * 64;
    ushort* Pl = Plds[w];
    const int wb = w * 512;

#define STAGE(bufi, kv0_)  do {                                        \
        const ushort* ks_ = KpB + (size_t)(kv0_) * 64 + tid * 8;       \
        const ushort* vs_ = VpB + (size_t)(kv0_) * 64 + tid * 8;       \
        gll16(ks_,        &Ks[bufi][wb]);                              \
        gll16(ks_ + 2048, &Ks[bufi][2048 + wb]);                       \
        gll16(vs_,        &Vs[bufi][wb]);                              \
        gll16(vs_ + 2048, &Vs[bufi][2048 + wb]);                       \
    } while (0)

    STAGE(0, 0);

    f32x4 ctxa[4] = {}, ctxb[4] = {};
    float m_a = -3.0e38f, m_b = -3.0e38f, l_a = 0.f, l_b = 0.f;
    int cur = 0;
    const int swq = q16 & 7;

    for (int kv0 = 0; kv0 < Seq; kv0 += 64) {
        __syncthreads();
        if (kv0 + 64 < Seq) STAGE(cur ^ 1, kv0 + 64);
        const ushort* Kt = Ks[cur];
        const ushort* Vt = Vs[cur];

        f32x4 sa[4] = {}, sb[4] = {};
#pragma unroll
        for (int t = 0; t < 4; t++) {
            const ushort* kr = Kt + (t * 16 + q16) * 64;
            bf16x8 ka = *(const bf16x8*)(kr + ((g ^ swq) * 8));
            bf16x8 kb = *(const bf16x8*)(kr + (((g + 4) ^ swq) * 8));
            sa[t] = __builtin_amdgcn_mfma_f32_16x16x32_bf16(ka, qa0, sa[t], 0, 0, 0);
            sa[t] = __builtin_amdgcn_mfma_f32_16x16x32_bf16(kb, qa1, sa[t], 0, 0, 0);
            sb[t] = __builtin_amdgcn_mfma_f32_16x16x32_bf16(ka, qb0, sb[t], 0, 0, 0);
            sb[t] = __builtin_amdgcn_mfma_f32_16x16x32_bf16(kb, qb1, sb[t], 0, 0, 0);
        }
        float ma = fmaxf(fmaxf(rmax4(sa[0]), rmax4(sa[1])), fmaxf(rmax4(sa[2]), rmax4(sa[3])));
        float mb = fmaxf(fmaxf(rmax4(sb[0]), rmax4(sb[1])), fmaxf(rmax4(sb[2]), rmax4(sb[3])));
        ma = fmaxf(ma, __shfl_xor(ma, 16)); ma = fmaxf(ma, __shfl_xor(ma, 32));
        mb = fmaxf(mb, __shfl_xor(mb, 16)); mb = fmaxf(mb, __shfl_xor(mb, 32));

        if (__any((ma > m_a + 8.f) | (mb > m_b + 8.f))) {
            float na = fmaxf(m_a, ma), nb = fmaxf(m_b, mb);
            float aa = EXP2(m_a - na), ab = EXP2(m_b - nb);
            float ala[4], alb[4];
#pragma unroll
            for (int i = 0; i < 4; i++) { ala[i] = __shfl(aa, g * 4 + i); alb[i] = __shfl(ab, g * 4 + i); }
#pragma unroll
            for (int n = 0; n < 4; n++)
#pragma unroll
                for (int i = 0; i < 4; i++) { ctxa[n][i] *= ala[i]; ctxb[n][i] *= alb[i]; }
            l_a *= aa; l_b *= ab;
            m_a = na; m_b = nb;
        }

        float lsa = 0.f, lsb = 0.f;
#pragma unroll
        for (int t = 0; t < 4; t++) {
            float p0 = EXP2(sa[t][0] - m_a), p1 = EXP2(sa[t][1] - m_a);
            float p2 = EXP2(sa[t][2] - m_a), p3 = EXP2(sa[t][3] - m_a);
            lsa += (p0 + p1) + (p2 + p3);
            uint2 pk; pk.x = cvt_pk_bf16(p0, p1); pk.y = cvt_pk_bf16(p2, p3);
            *(uint2*)(Pl + q16 * 72 + t * 16 + g * 4) = pk;
        }
#pragma unroll
        for (int t = 0; t < 4; t++) {
            float p0 = EXP2(sb[t][0] - m_b), p1 = EXP2(sb[t][1] - m_b);
            float p2 = EXP2(sb[t][2] - m_b), p3 = EXP2(sb[t][3] - m_b);
            lsb += (p0 + p1) + (p2 + p3);
            uint2 pk; pk.x = cvt_pk_bf16(p0, p1); pk.y = cvt_pk_bf16(p2, p3);
            *(uint2*)(Pl + (16 + q16) * 72 + t * 16 + g * 4) = pk;
        }
        l_a += lsa; l_b += lsb;

        bf16x8 paa0 = *(const bf16x8*)(Pl + q16 * 72 + g * 8);
        bf16x8 paa1 = *(const bf16x8*)(Pl + q16 * 72 + g * 8 + 32);
        bf16x8 pab0 = *(const bf16x8*)(Pl + (16 + q16) * 72 + g * 8);
        bf16x8 pab1 = *(const bf16x8*)(Pl + (16 + q16) * 72 + g * 8 + 32);
#pragma unroll
        for (int n = 0; n < 4; n++) {
            const ushort* vr = Vt + (n * 16 + q16) * 64;
            bf16x8 v0 = *(const bf16x8*)(vr + ((g ^ swq) * 8));
            bf16x8 v1 = *(const bf16x8*)(vr + (((g + 4) ^ swq) * 8));
            ctxa[n] = __builtin_amdgcn_mfma_f32_16x16x32_bf16(paa0, v0, ctxa[n], 0, 0, 0);
            ctxa[n] = __builtin_amdgcn_mfma_f32_16x16x32_bf16(paa1, v1, ctxa[n], 0, 0, 0);
            ctxb[n] = __builtin_amdgcn_mfma_f32_16x16x32_bf16(pab0, v0, ctxb[n], 0, 0, 0);
            ctxb[n] = __builtin_amdgcn_mfma_f32_16x16x32_bf16(pab1, v1, ctxb[n], 0, 0, 0);
        }
        cur ^= 1;
    }
#undef STAGE

    l_a += __shfl_xor(l_a, 16); l_a += __shfl_xor(l_a, 32);
    l_b += __shfl_xor(l_b, 16); l_b += __shfl_xor(l_b, 32);
    float rla = 1.f / l_a, rlb = 1.f / l_b;
    float ria[4], rib[4];
#pragma unroll
    for (int i = 0; i < 4; i++) { ria[i] = __shfl(rla, g * 4 + i); rib[i] = __shfl(rlb, g * 4 + i); }
    // Ctx written chunk-swizzled (it is gemm2's A operand)
#pragma unroll
    for (int n = 0; n < 4; n++) {
        int col = h * 64 + n * 16 + q16;
        int base = col & ~31, cc = (col >> 3) & 3, w8 = col & 7;
#pragma unroll
        for (int i = 0; i < 4; i++) {
            int ra = b * Seq + qrow + g * 4 + i;
            int rb2 = ra + 16;
            Ctx[(size_t)ra * Dim + base + ((cc ^ (ra & 3)) << 3) + w8]  = f2bf(ctxa[n][i] * ria[i]);
            Ctx[(size_t)rb2 * Dim + base + ((cc ^ (rb2 & 3)) << 3) + w8] = f2bf(ctxb[n][i] * rib[i]);
        }
    }
}

extern "C" void kernel_launch(void* const* d_in, const int* in_sizes, int n_in,
                              void* d_out, int out_size, void* d_ws, size_t ws_size,
                              hipStream_t stream) {
    const float* X  = (const float*)d_in[0];
    const float* Wq = (const float*)d_in[1];
    const float* bq = (const float*)d_in[2];
    const float* Wk = (const float*)d_in[3];
    const float* bk = (const float*)d_in[4];
    const float* Wv = (const float*)d_in[5];
    const float* bv = (const float*)d_in[6];
    const float* Wo = (const float*)d_in[7];
    const float* bo = (const float*)d_in[8];

    char* ws = (char*)d_ws;
    ushort* Xb    = (ushort*)(ws);                      //  8 MB (reused as Kp after QKV GEMM)
    ushort* Wtqkv = (ushort*)(ws + 8388608);            //  6 MB
    ushort* Wto   = (ushort*)(ws + 14680064);           //  2 MB
    float*  bqkv  = (float*)(ws + 16777216);            // 12 KB
    ushort* QKVb  = (ushort*)(ws + 16793600);           // 24 MB
    ushort* Vp    = (ushort*)(ws + 41959424);           //  8 MB
    ushort* Ctxb  = (ushort*)(ws + 50348032);           //  8 MB
    ushort* Kp    = Xb;                                 // alias: Xb dead after QKV GEMM

    convert_x<<<1024, 256, 0, stream>>>(X, Xb, Mtok * Dim / 16);
    dim3 tb(32, 8);
    transpose_w<<<dim3(32, 32), tb, 0, stream>>>(Wq, Wtqkv, QSCALE);
    transpose_w<<<dim3(32, 32), tb, 0, stream>>>(Wk, Wtqkv + 1024 * 1024, 1.f);
    transpose_w<<<dim3(32, 32), tb, 0, stream>>>(Wv, Wtqkv + 2 * 1024 * 1024, 1.f);
    transpose_w<<<dim3(32, 32), tb, 0, stream>>>(Wo, Wto, 1.f);
    concat_bias<<<12, 256, 0, stream>>>(bq, bk, bv, bqkv);

    gemm_bt<false><<<dim3(32, 24), 256, 0, stream>>>(Xb, Wtqkv, bqkv, QKVb, Mtok, NQKV, Dim);
    pack_kv<<<dim3(32, 32), 256, 0, stream>>>(QKVb, Kp, Vp);
    attn<<<dim3(16, 32), 256, 0, stream>>>(QKVb, Kp, Vp, Ctxb);
    gemm_bt<true><<<dim3(32, 8), 256, 0, stream>>>(Ctxb, Wto, bo, (float*)d_out, Mtok, Dim, Dim);
}